// Round 3
// baseline (411.998 us; speedup 1.0000x reference)
//
#include <hip/hip_runtime.h>
#include <stdint.h>

typedef unsigned short u16;
typedef __attribute__((ext_vector_type(8))) short bf16x8;
typedef __attribute__((ext_vector_type(4))) float f32x4;

#define S_LEN 4096
#define HID_DIM 2304
#define QKV_N 4096
#define AO_N 2048
#define HD 256
#define WIN 1024
#define QSCALE 0.0625f

static __device__ __forceinline__ u16 f2bf(float f) {
  union { float f; uint32_t u; } v; v.f = f;
  return (u16)((v.u + 0x7FFFu + ((v.u >> 16) & 1u)) >> 16);
}
static __device__ __forceinline__ float bf2f(u16 h) {
  union { uint32_t u; float f; } v; v.u = ((uint32_t)h) << 16;
  return v.f;
}

static __device__ __forceinline__ void gld16(const void* src, void* dst) {
  __builtin_amdgcn_global_load_lds((const __attribute__((address_space(1))) void*)src,
                                   (__attribute__((address_space(3))) void*)dst, 16, 0, 0);
}

// ---------------- fp32 -> bf16 elementwise ----------------
__global__ __launch_bounds__(256) void k_cvt_bf16(const float* __restrict__ in,
                                                  u16* __restrict__ out, int n) {
  int i = (blockIdx.x * 256 + threadIdx.x) * 4;
  if (i >= n) return;
  float4 v = *(const float4*)(in + i);
  uint64_t p = (uint64_t)f2bf(v.x) | ((uint64_t)f2bf(v.y) << 16)
             | ((uint64_t)f2bf(v.z) << 32) | ((uint64_t)f2bf(v.w) << 48);
  *(uint64_t*)(out + i) = p;
}

// in: fp32 [R][C] row-major; out bf16: out[(row_off + c)*out_stride + r] = in[r][c]
__global__ __launch_bounds__(256) void k_transpose_cvt(const float* __restrict__ in, int C,
                                                       u16* __restrict__ out, int out_stride,
                                                       int row_off) {
  __shared__ float tile[32][33];
  int c0 = blockIdx.x * 32, r0 = blockIdx.y * 32;
  int tx = threadIdx.x & 31, ty = threadIdx.x >> 5;
#pragma unroll
  for (int i = 0; i < 4; i++)
    tile[ty + i * 8][tx] = in[(size_t)(r0 + ty + i * 8) * C + c0 + tx];
  __syncthreads();
#pragma unroll
  for (int i = 0; i < 4; i++)
    out[(size_t)(row_off + c0 + ty + i * 8) * out_stride + r0 + tx] = f2bf(tile[tx][ty + i * 8]);
}

// ---------------- bf16 transpose of V block of qkv -> vt[kv*256 + d][s] ----------------
__global__ __launch_bounds__(256) void k_vtrans(const u16* __restrict__ qkv,
                                                u16* __restrict__ vtout) {
  __shared__ u16 tile[32][33];
  int c0 = blockIdx.x * 32, s0 = blockIdx.y * 32;
  int tx = threadIdx.x & 31, ty = threadIdx.x >> 5;
#pragma unroll
  for (int i = 0; i < 4; i++)
    tile[ty + i * 8][tx] = qkv[(size_t)(s0 + ty + i * 8) * QKV_N + 3072 + c0 + tx];
  __syncthreads();
#pragma unroll
  for (int i = 0; i < 4; i++)
    vtout[(size_t)(c0 + ty + i * 8) * S_LEN + s0 + tx] = tile[tx][ty + i * 8];
}

// ---------------- bf16 GEMM: C[M][N] = A[M][K] * Bt[N][K]^T ----------------
template <int OUT_BF16>
__global__ __launch_bounds__(256) void k_gemm_bt(const u16* __restrict__ A,
                                                 const u16* __restrict__ Bt,
                                                 void* __restrict__ Cout,
                                                 int M, int N, int K) {
  __shared__ u16 lA[128 * 32];
  __shared__ u16 lB[128 * 32];
  const int t = threadIdx.x;
  const int lane = t & 63, wave = t >> 6;
  const int wm = wave >> 1, wn = wave & 1;
  const int bm = blockIdx.y, bn = blockIdx.x;
  const int l15 = lane & 15, l4 = lane >> 4;
  f32x4 acc[4][4] = {};
  const int srow = wave * 32 + (lane >> 2), scol = (lane & 3) * 8;
  const u16* Ab = A + (size_t)(bm * 128 + srow) * K + scol;
  const u16* Bb = Bt + (size_t)(bn * 128 + srow) * K + scol;
  u16* lA0 = &lA[wave * 1024];
  u16* lB0 = &lB[wave * 1024];
  for (int k0 = 0; k0 < K; k0 += 32) {
    __syncthreads();
    gld16(Ab + k0, lA0);
    gld16(Ab + (size_t)16 * K + k0, lA0 + 512);
    gld16(Bb + k0, lB0);
    gld16(Bb + (size_t)16 * K + k0, lB0 + 512);
    __syncthreads();
    bf16x8 af[4], bfr[4];
#pragma unroll
    for (int i = 0; i < 4; i++)
      af[i] = *(const bf16x8*)&lA[(wm * 64 + i * 16 + l15) * 32 + l4 * 8];
#pragma unroll
    for (int j = 0; j < 4; j++)
      bfr[j] = *(const bf16x8*)&lB[(wn * 64 + j * 16 + l15) * 32 + l4 * 8];
#pragma unroll
    for (int i = 0; i < 4; i++)
#pragma unroll
      for (int j = 0; j < 4; j++)
        acc[i][j] = __builtin_amdgcn_mfma_f32_16x16x32_bf16(af[i], bfr[j], acc[i][j], 0, 0, 0);
  }
#pragma unroll
  for (int i = 0; i < 4; i++)
#pragma unroll
    for (int j = 0; j < 4; j++)
#pragma unroll
      for (int r = 0; r < 4; r++) {
        size_t row = bm * 128 + wm * 64 + i * 16 + l4 * 4 + r;
        size_t col = bn * 128 + wn * 64 + j * 16 + l15;
        if (OUT_BF16)
          ((u16*)Cout)[row * N + col] = f2bf(acc[i][j][r]);
        else
          ((float*)Cout)[row * N + col] = acc[i][j][r];
      }
}

// ---------------- fused RMSNorm + RoPE + scale, in place on bf16 q/k ----------------
__global__ __launch_bounds__(128) void k_normrope(u16* __restrict__ qkv,
                                                  const int* __restrict__ pos_ids,
                                                  const float* __restrict__ qw,
                                                  const float* __restrict__ kw) {
  __shared__ float cross[2];
  int idx = blockIdx.x;
  int s = idx / 12, r = idx % 12;
  bool is_q = (r < 8);
  u16* p = qkv + (size_t)s * QKV_N + (is_q ? r * HD : 2048 + (r - 8) * HD);
  const float* w = is_q ? qw : kw;
  int j = threadIdx.x;  // 0..127
  float x1 = bf2f(p[j]), x2 = bf2f(p[j + 128]);
  float ss = x1 * x1 + x2 * x2;
#pragma unroll
  for (int off = 1; off < 64; off <<= 1) ss += __shfl_xor(ss, off);
  if ((threadIdx.x & 63) == 0) cross[threadIdx.x >> 6] = ss;
  __syncthreads();
  float rms = rsqrtf((cross[0] + cross[1]) * (1.0f / 256.0f) + 1e-6f);
  float y1 = x1 * rms * (1.0f + w[j]);
  float y2 = x2 * rms * (1.0f + w[j + 128]);
  float ang = (float)pos_ids[s] * exp2f((float)j * (-13.287712379549449f / 128.0f));
  float sn, c;
  sincosf(ang, &sn, &c);
  float sc = is_q ? QSCALE : 1.0f;
  p[j] = f2bf((y1 * c - y2 * sn) * sc);
  p[j + 128] = f2bf((y1 * sn + y2 * c) * sc);
}

// ---------------- flash attention v3: sliding window, GQA ----------------
// block = (64 q, 1 head), 4 waves x 16 q-rows. KVBLK=64.
// K double-buffered in LDS via global_load_lds (pre-swizzled src, XOR (row&7)<<4 reads).
// V read directly from global V^T (32KB/tile slice -> L1/L2 resident), no LDS.
// LDS = 64K (K dbuf) + 8K (P) = 72KB -> 2 blocks/CU -> 2 waves/SIMD.
__global__ __launch_bounds__(256, 2) void k_attn(const u16* __restrict__ qkv,
                                                 const u16* __restrict__ vt,
                                                 const int* __restrict__ pos_ids,
                                                 u16* __restrict__ aout) {
  __shared__ u16 lK[2][64 * 256];  // [key][d], rows 512B, swizzled
  __shared__ u16 lP[4][16 * 64];   // per-wave P, rows 128B, swizzled
  const int h = blockIdx.y;
  const int q0 = blockIdx.x * 64;
  const int kvh = h >> 1;
  const int t = threadIdx.x, lane = t & 63, wave = t >> 6;
  const int l15 = lane & 15, l4 = lane >> 4;
  const int qw = q0 + wave * 16;

  // Q fragments (A-layout: row=lane&15, k=(lane>>4)*8+j)
  bf16x8 qfr[8];
  {
    const u16* qptr = qkv + (size_t)(qw + l15) * QKV_N + h * HD + l4 * 8;
#pragma unroll
    for (int kc = 0; kc < 8; kc++) qfr[kc] = *(const bf16x8*)(qptr + kc * 32);
  }
  f32x4 acc[16] = {};
  float mrow[4], lrow[4];
#pragma unroll
  for (int r = 0; r < 4; r++) { mrow[r] = -1e30f; lrow[r] = 0.0f; }
  int qi[4];
#pragma unroll
  for (int r = 0; r < 4; r++) qi[r] = pos_ids[qw + l4 * 4 + r];

  // K staging: 32 chunks of 1KB (2 rows x 512B); wave stages chunks wave*8..+7
  const int krw = lane >> 5, kcl = lane & 31;
  const u16* kgb = qkv + 2048 + kvh * HD;
  const u16* vgb = vt + ((size_t)kvh * HD + l15) * S_LEN + l4 * 8;  // + nd*16 rows + t0 + kc2*32

  int start = q0 - (WIN - 1);
  if (start < 0) start = 0;
  start &= ~63;

#define STAGE_K(B, T0) do {                                                           \
    _Pragma("unroll")                                                                 \
    for (int i_ = 0; i_ < 8; i_++) {                                                  \
      int ch_ = wave * 8 + i_;                                                        \
      int kr_ = ch_ * 2 + krw;                                                        \
      gld16(kgb + (size_t)((T0) + kr_) * QKV_N + ((kcl ^ (kr_ & 7)) * 8),             \
            &lK[B][ch_ * 512]);                                                       \
    }                                                                                 \
  } while (0)

  STAGE_K(0, start);
  __syncthreads();
  int buf = 0;
  for (int t0 = start; t0 <= q0 + 63; t0 += 64) {
    if (t0 + 64 <= q0 + 63) { int nb = buf ^ 1; STAGE_K(nb, t0 + 64); }
    int kp[4];
#pragma unroll
    for (int kb = 0; kb < 4; kb++) kp[kb] = pos_ids[t0 + kb * 16 + l15];
    // ---- S = Q K^T (4 key-blocks of 16) ----
    f32x4 sv[4] = {};
    __builtin_amdgcn_s_setprio(1);
#pragma unroll
    for (int kb = 0; kb < 4; kb++) {
      const char* krow = (const char*)&lK[buf][(kb * 16 + l15) * 256];
      const int sw = ((kb * 16 + l15) & 7) << 4;
#pragma unroll
      for (int kc = 0; kc < 8; kc++) {
        bf16x8 kf = *(const bf16x8*)(krow + ((kc * 64 + l4 * 16) ^ sw));
        sv[kb] = __builtin_amdgcn_mfma_f32_16x16x32_bf16(qfr[kc], kf, sv[kb], 0, 0, 0);
      }
    }
    __builtin_amdgcn_s_setprio(0);
    // ---- masked online softmax with defer-max (THR=8) ----
    float sloc[4][4], mx[4];
    float need = 0.0f;
#pragma unroll
    for (int r = 0; r < 4; r++) {
      int pi = qi[r];
#pragma unroll
      for (int kb = 0; kb < 4; kb++)
        sloc[r][kb] = ((kp[kb] <= pi) && (pi - kp[kb] < WIN)) ? sv[kb][r] : -__builtin_inff();
      float m_ = fmaxf(fmaxf(sloc[r][0], sloc[r][1]), fmaxf(sloc[r][2], sloc[r][3]));
#pragma unroll
      for (int off = 1; off < 16; off <<= 1) m_ = fmaxf(m_, __shfl_xor(m_, off));
      mx[r] = m_;
      need = fmaxf(need, m_ - mrow[r]);
    }
    bool resc = __any(need > 8.0f);
    if (resc) {
#pragma unroll
      for (int r = 0; r < 4; r++) {
        float nm = fmaxf(mrow[r], mx[r]);
        float al = __expf(mrow[r] - nm);
        mrow[r] = nm;
        lrow[r] *= al;
#pragma unroll
        for (int nd = 0; nd < 16; nd++) acc[nd][r] *= al;
      }
    }
#pragma unroll
    for (int r = 0; r < 4; r++) {
      float nm = mrow[r];
      float e0 = __expf(sloc[r][0] - nm), e1 = __expf(sloc[r][1] - nm);
      float e2 = __expf(sloc[r][2] - nm), e3 = __expf(sloc[r][3] - nm);
      float sum = (e0 + e1) + (e2 + e3);
#pragma unroll
      for (int off = 1; off < 16; off <<= 1) sum += __shfl_xor(sum, off);
      lrow[r] += sum;
      int q = l4 * 4 + r;
      char* lpw = (char*)&lP[wave][0] + q * 128;
      int swp = (q & 7) << 4;
      *(u16*)(lpw + ((l15 * 2) ^ swp)) = f2bf(e0);
      *(u16*)(lpw + ((32 + l15 * 2) ^ swp)) = f2bf(e1);
      *(u16*)(lpw + ((64 + l15 * 2) ^ swp)) = f2bf(e2);
      *(u16*)(lpw + ((96 + l15 * 2) ^ swp)) = f2bf(e3);
    }
    // ---- O += P V  (V B-frags direct from global V^T) ----
#pragma unroll
    for (int kc2 = 0; kc2 < 2; kc2++) {
      int q = l15;
      bf16x8 pa = *(const bf16x8*)((const char*)&lP[wave][0] + q * 128 +
                                   ((kc2 * 64 + l4 * 16) ^ ((q & 7) << 4)));
      __builtin_amdgcn_s_setprio(1);
#pragma unroll
      for (int nd = 0; nd < 16; nd++) {
        bf16x8 vf = *(const bf16x8*)(vgb + (size_t)(nd * 16) * S_LEN + t0 + kc2 * 32);
        acc[nd] = __builtin_amdgcn_mfma_f32_16x16x32_bf16(pa, vf, acc[nd], 0, 0, 0);
      }
      __builtin_amdgcn_s_setprio(0);
    }
    __syncthreads();  // staged nb complete + all reads of buf done
    buf ^= 1;
  }
  float rinv[4];
#pragma unroll
  for (int r = 0; r < 4; r++) rinv[r] = 1.0f / lrow[r];
#pragma unroll
  for (int nd = 0; nd < 16; nd++)
#pragma unroll
    for (int r = 0; r < 4; r++) {
      size_t row = qw + l4 * 4 + r;
      aout[row * AO_N + h * HD + nd * 16 + l15] = f2bf(acc[nd][r] * rinv[r]);
    }
#undef STAGE_K
}

extern "C" void kernel_launch(void* const* d_in, const int* in_sizes, int n_in,
                              void* d_out, int out_size, void* d_ws, size_t ws_size,
                              hipStream_t stream) {
  const float* x = (const float*)d_in[0];
  const int* pos = (const int*)d_in[1];
  const float* wq = (const float*)d_in[2];
  const float* wk = (const float*)d_in[3];
  const float* wv = (const float*)d_in[4];
  const float* wo = (const float*)d_in[5];
  const float* qnw = (const float*)d_in[6];
  const float* knw = (const float*)d_in[7];

  // scratch layout:
  //   d_out: qkv bf16 [4096][4096] (overwritten by final fp32 GEMM)
  //   ws+0        : x bf16 [4096][2304]; later aout bf16 [4096][2048]
  //   ws+18874368 : W^T bf16 (qkv-phase: [4096][2304]; out-phase: wo^T [2304][2048])
  //   ws+28311552 : vt bf16 [4][256][4096]
  u16* qkv = (u16*)d_out;
  u16* xbf = (u16*)d_ws;
  u16* wT = (u16*)((char*)d_ws + 18874368);
  u16* vtb = (u16*)((char*)d_ws + 28311552);
  u16* aout = xbf;

  k_cvt_bf16<<<9216, 256, 0, stream>>>(x, xbf, S_LEN * HID_DIM);
  k_transpose_cvt<<<dim3(64, 72), 256, 0, stream>>>(wq, 2048, wT, HID_DIM, 0);
  k_transpose_cvt<<<dim3(32, 72), 256, 0, stream>>>(wk, 1024, wT, HID_DIM, 2048);
  k_transpose_cvt<<<dim3(32, 72), 256, 0, stream>>>(wv, 1024, wT, HID_DIM, 3072);
  k_gemm_bt<1><<<dim3(32, 32), 256, 0, stream>>>(xbf, wT, qkv, S_LEN, QKV_N, HID_DIM);
  k_vtrans<<<dim3(32, 128), 256, 0, stream>>>(qkv, vtb);
  k_normrope<<<S_LEN * 12, 128, 0, stream>>>(qkv, pos, qnw, knw);
  k_attn<<<dim3(64, 8), 256, 0, stream>>>(qkv, vtb, pos, aout);
  k_transpose_cvt<<<dim3(72, 64), 256, 0, stream>>>(wo, HID_DIM, wT, 2048, 0);
  k_gemm_bt<0><<<dim3(18, 32), 256, 0, stream>>>(aout, wT, d_out, S_LEN, HID_DIM, 2048);
}

// Round 4
// 321.160 us; speedup vs baseline: 1.2828x; 1.2828x over previous
//
#include <hip/hip_runtime.h>
#include <stdint.h>

typedef unsigned short u16;
typedef __attribute__((ext_vector_type(8))) short bf16x8;
typedef __attribute__((ext_vector_type(4))) float f32x4;

#define S_LEN 4096
#define HID_DIM 2304
#define QKV_N 4096
#define AO_N 2048
#define HD 256
#define WIN 1024
#define QSCALE 0.0625f

static __device__ __forceinline__ u16 f2bf(float f) {
  union { float f; uint32_t u; } v; v.f = f;
  return (u16)((v.u + 0x7FFFu + ((v.u >> 16) & 1u)) >> 16);
}
static __device__ __forceinline__ float bf2f(u16 h) {
  union { uint32_t u; float f; } v; v.u = ((uint32_t)h) << 16;
  return v.f;
}

static __device__ __forceinline__ void gld16(const void* src, void* dst) {
  __builtin_amdgcn_global_load_lds((const __attribute__((address_space(1))) void*)src,
                                   (__attribute__((address_space(3))) void*)dst, 16, 0, 0);
}

// ---------------- fp32 -> bf16 elementwise ----------------
__global__ __launch_bounds__(256) void k_cvt_bf16(const float* __restrict__ in,
                                                  u16* __restrict__ out, int n) {
  int i = (blockIdx.x * 256 + threadIdx.x) * 4;
  if (i >= n) return;
  float4 v = *(const float4*)(in + i);
  uint64_t p = (uint64_t)f2bf(v.x) | ((uint64_t)f2bf(v.y) << 16)
             | ((uint64_t)f2bf(v.z) << 32) | ((uint64_t)f2bf(v.w) << 48);
  *(uint64_t*)(out + i) = p;
}

// in: fp32 [R][C] row-major; out bf16: out[(row_off + c)*out_stride + r] = in[r][c]
__global__ __launch_bounds__(256) void k_transpose_cvt(const float* __restrict__ in, int C,
                                                       u16* __restrict__ out, int out_stride,
                                                       int row_off) {
  __shared__ float tile[32][33];
  int c0 = blockIdx.x * 32, r0 = blockIdx.y * 32;
  int tx = threadIdx.x & 31, ty = threadIdx.x >> 5;
#pragma unroll
  for (int i = 0; i < 4; i++)
    tile[ty + i * 8][tx] = in[(size_t)(r0 + ty + i * 8) * C + c0 + tx];
  __syncthreads();
#pragma unroll
  for (int i = 0; i < 4; i++)
    out[(size_t)(row_off + c0 + ty + i * 8) * out_stride + r0 + tx] = f2bf(tile[tx][ty + i * 8]);
}

// ---------------- bf16 transpose of V block of qkv -> vt[kv*256 + d][s] ----------------
__global__ __launch_bounds__(256) void k_vtrans(const u16* __restrict__ qkv,
                                                u16* __restrict__ vtout) {
  __shared__ u16 tile[32][33];
  int c0 = blockIdx.x * 32, s0 = blockIdx.y * 32;
  int tx = threadIdx.x & 31, ty = threadIdx.x >> 5;
#pragma unroll
  for (int i = 0; i < 4; i++)
    tile[ty + i * 8][tx] = qkv[(size_t)(s0 + ty + i * 8) * QKV_N + 3072 + c0 + tx];
  __syncthreads();
#pragma unroll
  for (int i = 0; i < 4; i++)
    vtout[(size_t)(c0 + ty + i * 8) * S_LEN + s0 + tx] = tile[tx][ty + i * 8];
}

// ---------------- bf16 GEMM: C[M][N] = A[M][K] * Bt[N][K]^T ----------------
template <int OUT_BF16>
__global__ __launch_bounds__(256) void k_gemm_bt(const u16* __restrict__ A,
                                                 const u16* __restrict__ Bt,
                                                 void* __restrict__ Cout,
                                                 int M, int N, int K) {
  __shared__ u16 lA[128 * 32];
  __shared__ u16 lB[128 * 32];
  const int t = threadIdx.x;
  const int lane = t & 63, wave = t >> 6;
  const int wm = wave >> 1, wn = wave & 1;
  const int bm = blockIdx.y, bn = blockIdx.x;
  const int l15 = lane & 15, l4 = lane >> 4;
  f32x4 acc[4][4] = {};
  const int srow = wave * 32 + (lane >> 2), scol = (lane & 3) * 8;
  const u16* Ab = A + (size_t)(bm * 128 + srow) * K + scol;
  const u16* Bb = Bt + (size_t)(bn * 128 + srow) * K + scol;
  u16* lA0 = &lA[wave * 1024];
  u16* lB0 = &lB[wave * 1024];
  for (int k0 = 0; k0 < K; k0 += 32) {
    __syncthreads();
    gld16(Ab + k0, lA0);
    gld16(Ab + (size_t)16 * K + k0, lA0 + 512);
    gld16(Bb + k0, lB0);
    gld16(Bb + (size_t)16 * K + k0, lB0 + 512);
    __syncthreads();
    bf16x8 af[4], bfr[4];
#pragma unroll
    for (int i = 0; i < 4; i++)
      af[i] = *(const bf16x8*)&lA[(wm * 64 + i * 16 + l15) * 32 + l4 * 8];
#pragma unroll
    for (int j = 0; j < 4; j++)
      bfr[j] = *(const bf16x8*)&lB[(wn * 64 + j * 16 + l15) * 32 + l4 * 8];
#pragma unroll
    for (int i = 0; i < 4; i++)
#pragma unroll
      for (int j = 0; j < 4; j++)
        acc[i][j] = __builtin_amdgcn_mfma_f32_16x16x32_bf16(af[i], bfr[j], acc[i][j], 0, 0, 0);
  }
#pragma unroll
  for (int i = 0; i < 4; i++)
#pragma unroll
    for (int j = 0; j < 4; j++)
#pragma unroll
      for (int r = 0; r < 4; r++) {
        size_t row = bm * 128 + wm * 64 + i * 16 + l4 * 4 + r;
        size_t col = bn * 128 + wn * 64 + j * 16 + l15;
        if (OUT_BF16)
          ((u16*)Cout)[row * N + col] = f2bf(acc[i][j][r]);
        else
          ((float*)Cout)[row * N + col] = acc[i][j][r];
      }
}

// ---------------- fused RMSNorm + RoPE + scale, in place on bf16 q/k ----------------
__global__ __launch_bounds__(128) void k_normrope(u16* __restrict__ qkv,
                                                  const int* __restrict__ pos_ids,
                                                  const float* __restrict__ qw,
                                                  const float* __restrict__ kw) {
  __shared__ float cross[2];
  int idx = blockIdx.x;
  int s = idx / 12, r = idx % 12;
  bool is_q = (r < 8);
  u16* p = qkv + (size_t)s * QKV_N + (is_q ? r * HD : 2048 + (r - 8) * HD);
  const float* w = is_q ? qw : kw;
  int j = threadIdx.x;  // 0..127
  float x1 = bf2f(p[j]), x2 = bf2f(p[j + 128]);
  float ss = x1 * x1 + x2 * x2;
#pragma unroll
  for (int off = 1; off < 64; off <<= 1) ss += __shfl_xor(ss, off);
  if ((threadIdx.x & 63) == 0) cross[threadIdx.x >> 6] = ss;
  __syncthreads();
  float rms = rsqrtf((cross[0] + cross[1]) * (1.0f / 256.0f) + 1e-6f);
  float y1 = x1 * rms * (1.0f + w[j]);
  float y2 = x2 * rms * (1.0f + w[j + 128]);
  float ang = (float)pos_ids[s] * exp2f((float)j * (-13.287712379549449f / 128.0f));
  float sn, c;
  sincosf(ang, &sn, &c);
  float sc = is_q ? QSCALE : 1.0f;
  p[j] = f2bf((y1 * c - y2 * sn) * sc);
  p[j + 128] = f2bf((y1 * sn + y2 * c) * sc);
}

// ---------------- flash attention v4: sliding window, GQA-shared K/V ----------------
// block = (32 q x 1 kv-head, BOTH q-heads): wave w -> head kvh*2+(w>>1), rows q0+(w&1)*16.
// K,V single-buffered in LDS (32KB+32KB, gld_lds pre-swizzled src, XOR (row&7)<<4 reads),
// lP 8KB -> 72KB total -> 2 blocks/CU (2 waves/SIMD). Grid 512, bijective XCD swizzle.
__global__ __launch_bounds__(256, 2) void k_attn(const u16* __restrict__ qkv,
                                                 const u16* __restrict__ vt,
                                                 const int* __restrict__ pos_ids,
                                                 u16* __restrict__ aout) {
  __shared__ u16 lK[64 * 256];   // [key][d], rows 512B, swizzled
  __shared__ u16 lV[256 * 64];   // [d][key], rows 128B, swizzled
  __shared__ u16 lP[4][16 * 64]; // per-wave P, rows 128B, swizzled
  // XCD-bijective swizzle: nwg=512 -> xcd gets 64 consecutive logical ids
  const int bid = blockIdx.x;
  const int wg = (bid & 7) * 64 + (bid >> 3);
  const int kvh = wg >> 7;           // 0..3
  const int q0 = (wg & 127) * 32;    // 0..4064
  const int t = threadIdx.x, lane = t & 63, wave = t >> 6;
  const int l15 = lane & 15, l4 = lane >> 4;
  const int head = kvh * 2 + (wave >> 1);
  const int qw = q0 + (wave & 1) * 16;

  // Q fragments (A-layout: row=lane&15, k=(lane>>4)*8+j)
  bf16x8 qfr[8];
  {
    const u16* qptr = qkv + (size_t)(qw + l15) * QKV_N + head * HD + l4 * 8;
#pragma unroll
    for (int kc = 0; kc < 8; kc++) qfr[kc] = *(const bf16x8*)(qptr + kc * 32);
  }
  f32x4 acc[16] = {};
  float mrow[4], lrow[4];
#pragma unroll
  for (int r = 0; r < 4; r++) { mrow[r] = -1e30f; lrow[r] = 0.0f; }
  int qi[4];
#pragma unroll
  for (int r = 0; r < 4; r++) qi[r] = pos_ids[qw + l4 * 4 + r];

  // staging lane maps: K chunk=1KB=2 rows x 512B; V chunk=1KB=8 rows x 128B
  const int krw = lane >> 5, kcl = lane & 31;
  const int vrw = lane >> 3, vcl = lane & 7;
  const u16* kgb = qkv + 2048 + kvh * HD;
  const u16* vgb = vt + (size_t)kvh * HD * S_LEN;

  int start = q0 - (WIN - 1);
  if (start < 0) start = 0;
  start &= ~63;

#define STAGE_KV(T0) do {                                                             \
    _Pragma("unroll")                                                                 \
    for (int i_ = 0; i_ < 8; i_++) {                                                  \
      int ch_ = wave * 8 + i_;                                                        \
      int kr_ = ch_ * 2 + krw;                                                        \
      gld16(kgb + (size_t)((T0) + kr_) * QKV_N + ((kcl ^ (kr_ & 7)) * 8),             \
            &lK[ch_ * 512]);                                                          \
      int vr_ = ch_ * 8 + vrw;                                                        \
      gld16(vgb + (size_t)vr_ * S_LEN + (T0) + ((vcl ^ (vr_ & 7)) * 8),               \
            &lV[ch_ * 512]);                                                          \
    }                                                                                 \
  } while (0)

  for (int t0 = start; t0 <= q0 + 31; t0 += 64) {
    STAGE_KV(t0);
    int kp[4];
#pragma unroll
    for (int kb = 0; kb < 4; kb++) kp[kb] = pos_ids[t0 + kb * 16 + l15];
    __syncthreads();  // drains vmcnt+lgkm -> staged K/V visible
    // ---- S = Q K^T (4 key-blocks of 16) ----
    f32x4 sv[4] = {};
    __builtin_amdgcn_s_setprio(1);
#pragma unroll
    for (int kb = 0; kb < 4; kb++) {
      const char* krow = (const char*)&lK[(kb * 16 + l15) * 256];
      const int sw = ((kb * 16 + l15) & 7) << 4;
#pragma unroll
      for (int kc = 0; kc < 8; kc++) {
        bf16x8 kf = *(const bf16x8*)(krow + ((kc * 64 + l4 * 16) ^ sw));
        sv[kb] = __builtin_amdgcn_mfma_f32_16x16x32_bf16(qfr[kc], kf, sv[kb], 0, 0, 0);
      }
    }
    __builtin_amdgcn_s_setprio(0);
    // ---- masked online softmax with defer-max (THR=8) ----
    float sloc[4][4], mx[4];
    float need = 0.0f;
#pragma unroll
    for (int r = 0; r < 4; r++) {
      int pi = qi[r];
#pragma unroll
      for (int kb = 0; kb < 4; kb++)
        sloc[r][kb] = ((kp[kb] <= pi) && (pi - kp[kb] < WIN)) ? sv[kb][r] : -__builtin_inff();
      float m_ = fmaxf(fmaxf(sloc[r][0], sloc[r][1]), fmaxf(sloc[r][2], sloc[r][3]));
#pragma unroll
      for (int off = 1; off < 16; off <<= 1) m_ = fmaxf(m_, __shfl_xor(m_, off));
      mx[r] = m_;
      need = fmaxf(need, m_ - mrow[r]);
    }
    bool resc = __any(need > 8.0f);
    if (resc) {
#pragma unroll
      for (int r = 0; r < 4; r++) {
        float nm = fmaxf(mrow[r], mx[r]);
        float al = __expf(mrow[r] - nm);
        mrow[r] = nm;
        lrow[r] *= al;
#pragma unroll
        for (int nd = 0; nd < 16; nd++) acc[nd][r] *= al;
      }
    }
#pragma unroll
    for (int r = 0; r < 4; r++) {
      float nm = mrow[r];
      float e0 = __expf(sloc[r][0] - nm), e1 = __expf(sloc[r][1] - nm);
      float e2 = __expf(sloc[r][2] - nm), e3 = __expf(sloc[r][3] - nm);
      float sum = (e0 + e1) + (e2 + e3);
#pragma unroll
      for (int off = 1; off < 16; off <<= 1) sum += __shfl_xor(sum, off);
      lrow[r] += sum;
      int q = l4 * 4 + r;
      char* lpw = (char*)&lP[wave][0] + q * 128;
      int swp = (q & 7) << 4;
      *(u16*)(lpw + ((l15 * 2) ^ swp)) = f2bf(e0);
      *(u16*)(lpw + ((32 + l15 * 2) ^ swp)) = f2bf(e1);
      *(u16*)(lpw + ((64 + l15 * 2) ^ swp)) = f2bf(e2);
      *(u16*)(lpw + ((96 + l15 * 2) ^ swp)) = f2bf(e3);
    }
    // ---- O += P V ----
#pragma unroll
    for (int kc2 = 0; kc2 < 2; kc2++) {
      int q = l15;
      bf16x8 pa = *(const bf16x8*)((const char*)&lP[wave][0] + q * 128 +
                                   ((kc2 * 64 + l4 * 16) ^ ((q & 7) << 4)));
      __builtin_amdgcn_s_setprio(1);
#pragma unroll
      for (int nd = 0; nd < 16; nd++) {
        int d = nd * 16 + l15;
        bf16x8 vf = *(const bf16x8*)((const char*)&lV[d * 64] +
                                     ((kc2 * 64 + l4 * 16) ^ ((d & 7) << 4)));
        acc[nd] = __builtin_amdgcn_mfma_f32_16x16x32_bf16(pa, vf, acc[nd], 0, 0, 0);
      }
      __builtin_amdgcn_s_setprio(0);
    }
    __syncthreads();  // all reads of lK/lV done before next stage overwrites
  }
  float rinv[4];
#pragma unroll
  for (int r = 0; r < 4; r++) rinv[r] = 1.0f / lrow[r];
#pragma unroll
  for (int nd = 0; nd < 16; nd++)
#pragma unroll
    for (int r = 0; r < 4; r++) {
      size_t row = qw + l4 * 4 + r;
      aout[row * AO_N + head * HD + nd * 16 + l15] = f2bf(acc[nd][r] * rinv[r]);
    }
#undef STAGE_KV
}

extern "C" void kernel_launch(void* const* d_in, const int* in_sizes, int n_in,
                              void* d_out, int out_size, void* d_ws, size_t ws_size,
                              hipStream_t stream) {
  const float* x = (const float*)d_in[0];
  const int* pos = (const int*)d_in[1];
  const float* wq = (const float*)d_in[2];
  const float* wk = (const float*)d_in[3];
  const float* wv = (const float*)d_in[4];
  const float* wo = (const float*)d_in[5];
  const float* qnw = (const float*)d_in[6];
  const float* knw = (const float*)d_in[7];

  // scratch layout:
  //   d_out: qkv bf16 [4096][4096] (overwritten by final fp32 GEMM)
  //   ws+0        : x bf16 [4096][2304]; later aout bf16 [4096][2048]
  //   ws+18874368 : W^T bf16 (qkv-phase: [4096][2304]; out-phase: wo^T [2304][2048])
  //   ws+28311552 : vt bf16 [4][256][4096]
  u16* qkv = (u16*)d_out;
  u16* xbf = (u16*)d_ws;
  u16* wT = (u16*)((char*)d_ws + 18874368);
  u16* vtb = (u16*)((char*)d_ws + 28311552);
  u16* aout = xbf;

  k_cvt_bf16<<<9216, 256, 0, stream>>>(x, xbf, S_LEN * HID_DIM);
  k_transpose_cvt<<<dim3(64, 72), 256, 0, stream>>>(wq, 2048, wT, HID_DIM, 0);
  k_transpose_cvt<<<dim3(32, 72), 256, 0, stream>>>(wk, 1024, wT, HID_DIM, 2048);
  k_transpose_cvt<<<dim3(32, 72), 256, 0, stream>>>(wv, 1024, wT, HID_DIM, 3072);
  k_gemm_bt<1><<<dim3(32, 32), 256, 0, stream>>>(xbf, wT, qkv, S_LEN, QKV_N, HID_DIM);
  k_vtrans<<<dim3(32, 128), 256, 0, stream>>>(qkv, vtb);
  k_normrope<<<S_LEN * 12, 128, 0, stream>>>(qkv, pos, qnw, knw);
  k_attn<<<dim3(512), 256, 0, stream>>>(qkv, vtb, pos, aout);
  k_transpose_cvt<<<dim3(72, 64), 256, 0, stream>>>(wo, HID_DIM, wT, 2048, 0);
  k_gemm_bt<0><<<dim3(18, 32), 256, 0, stream>>>(aout, wT, d_out, S_LEN, HID_DIM, 2048);
}

// Round 5
// 297.678 us; speedup vs baseline: 1.3840x; 1.0789x over previous
//
#include <hip/hip_runtime.h>
#include <stdint.h>

typedef unsigned short u16;
typedef __attribute__((ext_vector_type(8))) short bf16x8;
typedef __attribute__((ext_vector_type(4))) float f32x4;

#define S_LEN 4096
#define HID_DIM 2304
#define QKV_N 4096
#define AO_N 2048
#define HD 256
#define WIN 1024
#define QSCALE 0.0625f

static __device__ __forceinline__ u16 f2bf(float f) {
  union { float f; uint32_t u; } v; v.f = f;
  return (u16)((v.u + 0x7FFFu + ((v.u >> 16) & 1u)) >> 16);
}
static __device__ __forceinline__ float bf2f(u16 h) {
  union { uint32_t u; float f; } v; v.u = ((uint32_t)h) << 16;
  return v.f;
}

static __device__ __forceinline__ void gld16(const void* src, void* dst) {
  __builtin_amdgcn_global_load_lds((const __attribute__((address_space(1))) void*)src,
                                   (__attribute__((address_space(3))) void*)dst, 16, 0, 0);
}

// ---------------- fp32 -> bf16 elementwise ----------------
__global__ __launch_bounds__(256) void k_cvt_bf16(const float* __restrict__ in,
                                                  u16* __restrict__ out, int n) {
  int i = (blockIdx.x * 256 + threadIdx.x) * 4;
  if (i >= n) return;
  float4 v = *(const float4*)(in + i);
  uint64_t p = (uint64_t)f2bf(v.x) | ((uint64_t)f2bf(v.y) << 16)
             | ((uint64_t)f2bf(v.z) << 32) | ((uint64_t)f2bf(v.w) << 48);
  *(uint64_t*)(out + i) = p;
}

// in: fp32 [R][C] row-major; out bf16: out[(row_off + c)*out_stride + r] = in[r][c]
__global__ __launch_bounds__(256) void k_transpose_cvt(const float* __restrict__ in, int C,
                                                       u16* __restrict__ out, int out_stride,
                                                       int row_off) {
  __shared__ float tile[32][33];
  int c0 = blockIdx.x * 32, r0 = blockIdx.y * 32;
  int tx = threadIdx.x & 31, ty = threadIdx.x >> 5;
#pragma unroll
  for (int i = 0; i < 4; i++)
    tile[ty + i * 8][tx] = in[(size_t)(r0 + ty + i * 8) * C + c0 + tx];
  __syncthreads();
#pragma unroll
  for (int i = 0; i < 4; i++)
    out[(size_t)(row_off + c0 + ty + i * 8) * out_stride + r0 + tx] = f2bf(tile[tx][ty + i * 8]);
}

// ---------------- bf16 transpose of V block of qkv -> vt[kv*256 + d][s] ----------------
__global__ __launch_bounds__(256) void k_vtrans(const u16* __restrict__ qkv,
                                                u16* __restrict__ vtout) {
  __shared__ u16 tile[32][33];
  int c0 = blockIdx.x * 32, s0 = blockIdx.y * 32;
  int tx = threadIdx.x & 31, ty = threadIdx.x >> 5;
#pragma unroll
  for (int i = 0; i < 4; i++)
    tile[ty + i * 8][tx] = qkv[(size_t)(s0 + ty + i * 8) * QKV_N + 3072 + c0 + tx];
  __syncthreads();
#pragma unroll
  for (int i = 0; i < 4; i++)
    vtout[(size_t)(c0 + ty + i * 8) * S_LEN + s0 + tx] = tile[tx][ty + i * 8];
}

// ---------------- bf16 GEMM v2: C[M][N] = A[M][K] * Bt[N][K]^T ----------------
// 256x256 tile, BK=32, 512 thr = 8 waves (2Mx4N), wave tile 128x64 (acc[8][4]).
// Ring of 4 LDS K-tiles (sA/sB 16KB each -> 128KB). Stage tile t+3 while computing t
// via global_load_lds w/ pre-swizzled source; boundary = counted vmcnt(8) + raw barrier
// (never drains to 0 in steady state). LDS reads XOR-swizzled: slot ^= (row>>1)&3.
template <int OUT_BF16>
__global__ __launch_bounds__(512, 2) void k_gemm256(const u16* __restrict__ A,
                                                    const u16* __restrict__ Bt,
                                                    void* __restrict__ Cout,
                                                    int M, int N, int K) {
  __shared__ u16 sA[4][256 * 32];
  __shared__ u16 sB[4][256 * 32];
  const int t = threadIdx.x, lane = t & 63, wave = t >> 6;
  const int wr = wave >> 2, wc = wave & 3;  // 2 x 4 wave grid
  const int l15 = lane & 15, l4 = lane >> 4;
  const int nbn = N >> 8;
  const int cpx = gridDim.x >> 3;
  const int wg = (blockIdx.x & 7) * cpx + (blockIdx.x >> 3);  // bijective XCD swizzle
  const int bm = wg / nbn, bn = wg % nbn;
  // staging: chunk = 1KB = 16 rows x 64B; lane -> row = lane>>2, 16B-slot = lane&3.
  // source col pre-swizzled so that LDS(row,slot) holds elem (row, (slot^((row>>1)&3))*8)
  const int srow = lane >> 2;
  const int scol = ((lane & 3) ^ ((lane >> 3) & 3)) * 8;
  const u16* Ab = A + (size_t)(bm * 256 + srow) * K + scol;
  const u16* Bb = Bt + (size_t)(bn * 256 + srow) * K + scol;
  const int NT = K >> 5;
  f32x4 acc[8][4] = {};

#define G256_STAGE(TT) do {                                                   \
    int r_ = (TT) & 3, k0_ = (TT) << 5;                                       \
    _Pragma("unroll")                                                         \
    for (int c_ = 0; c_ < 2; c_++) {                                          \
      int ch_ = wave * 2 + c_;                                                \
      gld16(Ab + (size_t)(ch_ * 16) * K + k0_, &sA[r_][ch_ * 512]);           \
      gld16(Bb + (size_t)(ch_ * 16) * K + k0_, &sB[r_][ch_ * 512]);           \
    }                                                                         \
  } while (0)

  G256_STAGE(0);
  G256_STAGE(1);
  G256_STAGE(2);
  asm volatile("s_waitcnt vmcnt(8)" ::: "memory");  // tile 0 resident
  __builtin_amdgcn_s_barrier();

  // read offset within a row: 16B slot l4, XOR'd with ((row>>1)&3); row = *+l15 so
  // (row>>1)&3 == (l15>>1)&3 for all frag bases (multiples of 8 rows).
  const int lxo = (l4 * 16) ^ (((l15 >> 1) & 3) << 4);

  for (int tt = 0; tt < NT; ++tt) {
    if (tt + 3 < NT) G256_STAGE(tt + 3);
    const char* pa = (const char*)&sA[tt & 3][0] + (wr * 128 + l15) * 64 + lxo;
    const char* pb = (const char*)&sB[tt & 3][0] + (wc * 64 + l15) * 64 + lxo;
    bf16x8 af[8], bfr[4];
#pragma unroll
    for (int m = 0; m < 8; m++) af[m] = *(const bf16x8*)(pa + m * 1024);
#pragma unroll
    for (int n = 0; n < 4; n++) bfr[n] = *(const bf16x8*)(pb + n * 1024);
    __builtin_amdgcn_s_setprio(1);
#pragma unroll
    for (int m = 0; m < 8; m++)
#pragma unroll
      for (int n = 0; n < 4; n++)
        acc[m][n] = __builtin_amdgcn_mfma_f32_16x16x32_bf16(af[m], bfr[n], acc[m][n], 0, 0, 0);
    __builtin_amdgcn_s_setprio(0);
    int rem = NT - 1 - tt;
    if (rem > 0) {
      // wait until tile tt+1 resident: younger loads = 4 * (#tiles staged beyond tt+1)
      if (rem >= 3)
        asm volatile("s_waitcnt vmcnt(8)" ::: "memory");
      else if (rem == 2)
        asm volatile("s_waitcnt vmcnt(4)" ::: "memory");
      else
        asm volatile("s_waitcnt vmcnt(0)" ::: "memory");
      __builtin_amdgcn_s_barrier();
    }
  }
#undef G256_STAGE

#pragma unroll
  for (int m = 0; m < 8; m++)
#pragma unroll
    for (int n = 0; n < 4; n++)
#pragma unroll
      for (int r = 0; r < 4; r++) {
        size_t row = bm * 256 + wr * 128 + m * 16 + l4 * 4 + r;
        size_t col = bn * 256 + wc * 64 + n * 16 + l15;
        if (OUT_BF16)
          ((u16*)Cout)[row * N + col] = f2bf(acc[m][n][r]);
        else
          ((float*)Cout)[row * N + col] = acc[m][n][r];
      }
}

// ---------------- fused RMSNorm + RoPE + scale, in place on bf16 q/k ----------------
__global__ __launch_bounds__(128) void k_normrope(u16* __restrict__ qkv,
                                                  const int* __restrict__ pos_ids,
                                                  const float* __restrict__ qw,
                                                  const float* __restrict__ kw) {
  __shared__ float cross[2];
  int idx = blockIdx.x;
  int s = idx / 12, r = idx % 12;
  bool is_q = (r < 8);
  u16* p = qkv + (size_t)s * QKV_N + (is_q ? r * HD : 2048 + (r - 8) * HD);
  const float* w = is_q ? qw : kw;
  int j = threadIdx.x;  // 0..127
  float x1 = bf2f(p[j]), x2 = bf2f(p[j + 128]);
  float ss = x1 * x1 + x2 * x2;
#pragma unroll
  for (int off = 1; off < 64; off <<= 1) ss += __shfl_xor(ss, off);
  if ((threadIdx.x & 63) == 0) cross[threadIdx.x >> 6] = ss;
  __syncthreads();
  float rms = rsqrtf((cross[0] + cross[1]) * (1.0f / 256.0f) + 1e-6f);
  float y1 = x1 * rms * (1.0f + w[j]);
  float y2 = x2 * rms * (1.0f + w[j + 128]);
  float ang = (float)pos_ids[s] * exp2f((float)j * (-13.287712379549449f / 128.0f));
  float sn, c;
  sincosf(ang, &sn, &c);
  float sc = is_q ? QSCALE : 1.0f;
  p[j] = f2bf((y1 * c - y2 * sn) * sc);
  p[j + 128] = f2bf((y1 * sn + y2 * c) * sc);
}

// ---------------- flash attention v4: sliding window, GQA-shared K/V ----------------
__global__ __launch_bounds__(256, 2) void k_attn(const u16* __restrict__ qkv,
                                                 const u16* __restrict__ vt,
                                                 const int* __restrict__ pos_ids,
                                                 u16* __restrict__ aout) {
  __shared__ u16 lK[64 * 256];   // [key][d], rows 512B, swizzled
  __shared__ u16 lV[256 * 64];   // [d][key], rows 128B, swizzled
  __shared__ u16 lP[4][16 * 64]; // per-wave P, rows 128B, swizzled
  const int bid = blockIdx.x;
  const int wg = (bid & 7) * 64 + (bid >> 3);
  const int kvh = wg >> 7;
  const int q0 = (wg & 127) * 32;
  const int t = threadIdx.x, lane = t & 63, wave = t >> 6;
  const int l15 = lane & 15, l4 = lane >> 4;
  const int head = kvh * 2 + (wave >> 1);
  const int qw = q0 + (wave & 1) * 16;

  bf16x8 qfr[8];
  {
    const u16* qptr = qkv + (size_t)(qw + l15) * QKV_N + head * HD + l4 * 8;
#pragma unroll
    for (int kc = 0; kc < 8; kc++) qfr[kc] = *(const bf16x8*)(qptr + kc * 32);
  }
  f32x4 acc[16] = {};
  float mrow[4], lrow[4];
#pragma unroll
  for (int r = 0; r < 4; r++) { mrow[r] = -1e30f; lrow[r] = 0.0f; }
  int qi[4];
#pragma unroll
  for (int r = 0; r < 4; r++) qi[r] = pos_ids[qw + l4 * 4 + r];

  const int krw = lane >> 5, kcl = lane & 31;
  const int vrw = lane >> 3, vcl = lane & 7;
  const u16* kgb = qkv + 2048 + kvh * HD;
  const u16* vgb = vt + (size_t)kvh * HD * S_LEN;

  int start = q0 - (WIN - 1);
  if (start < 0) start = 0;
  start &= ~63;

#define STAGE_KV(T0) do {                                                             \
    _Pragma("unroll")                                                                 \
    for (int i_ = 0; i_ < 8; i_++) {                                                  \
      int ch_ = wave * 8 + i_;                                                        \
      int kr_ = ch_ * 2 + krw;                                                        \
      gld16(kgb + (size_t)((T0) + kr_) * QKV_N + ((kcl ^ (kr_ & 7)) * 8),             \
            &lK[ch_ * 512]);                                                          \
      int vr_ = ch_ * 8 + vrw;                                                        \
      gld16(vgb + (size_t)vr_ * S_LEN + (T0) + ((vcl ^ (vr_ & 7)) * 8),               \
            &lV[ch_ * 512]);                                                          \
    }                                                                                 \
  } while (0)

  for (int t0 = start; t0 <= q0 + 31; t0 += 64) {
    STAGE_KV(t0);
    int kp[4];
#pragma unroll
    for (int kb = 0; kb < 4; kb++) kp[kb] = pos_ids[t0 + kb * 16 + l15];
    __syncthreads();
    f32x4 sv[4] = {};
    __builtin_amdgcn_s_setprio(1);
#pragma unroll
    for (int kb = 0; kb < 4; kb++) {
      const char* krow = (const char*)&lK[(kb * 16 + l15) * 256];
      const int sw = ((kb * 16 + l15) & 7) << 4;
#pragma unroll
      for (int kc = 0; kc < 8; kc++) {
        bf16x8 kf = *(const bf16x8*)(krow + ((kc * 64 + l4 * 16) ^ sw));
        sv[kb] = __builtin_amdgcn_mfma_f32_16x16x32_bf16(qfr[kc], kf, sv[kb], 0, 0, 0);
      }
    }
    __builtin_amdgcn_s_setprio(0);
    float sloc[4][4], mx[4];
    float need = 0.0f;
#pragma unroll
    for (int r = 0; r < 4; r++) {
      int pi = qi[r];
#pragma unroll
      for (int kb = 0; kb < 4; kb++)
        sloc[r][kb] = ((kp[kb] <= pi) && (pi - kp[kb] < WIN)) ? sv[kb][r] : -__builtin_inff();
      float m_ = fmaxf(fmaxf(sloc[r][0], sloc[r][1]), fmaxf(sloc[r][2], sloc[r][3]));
#pragma unroll
      for (int off = 1; off < 16; off <<= 1) m_ = fmaxf(m_, __shfl_xor(m_, off));
      mx[r] = m_;
      need = fmaxf(need, m_ - mrow[r]);
    }
    bool resc = __any(need > 8.0f);
    if (resc) {
#pragma unroll
      for (int r = 0; r < 4; r++) {
        float nm = fmaxf(mrow[r], mx[r]);
        float al = __expf(mrow[r] - nm);
        mrow[r] = nm;
        lrow[r] *= al;
#pragma unroll
        for (int nd = 0; nd < 16; nd++) acc[nd][r] *= al;
      }
    }
#pragma unroll
    for (int r = 0; r < 4; r++) {
      float nm = mrow[r];
      float e0 = __expf(sloc[r][0] - nm), e1 = __expf(sloc[r][1] - nm);
      float e2 = __expf(sloc[r][2] - nm), e3 = __expf(sloc[r][3] - nm);
      float sum = (e0 + e1) + (e2 + e3);
#pragma unroll
      for (int off = 1; off < 16; off <<= 1) sum += __shfl_xor(sum, off);
      lrow[r] += sum;
      int q = l4 * 4 + r;
      char* lpw = (char*)&lP[wave][0] + q * 128;
      int swp = (q & 7) << 4;
      *(u16*)(lpw + ((l15 * 2) ^ swp)) = f2bf(e0);
      *(u16*)(lpw + ((32 + l15 * 2) ^ swp)) = f2bf(e1);
      *(u16*)(lpw + ((64 + l15 * 2) ^ swp)) = f2bf(e2);
      *(u16*)(lpw + ((96 + l15 * 2) ^ swp)) = f2bf(e3);
    }
#pragma unroll
    for (int kc2 = 0; kc2 < 2; kc2++) {
      int q = l15;
      bf16x8 pa = *(const bf16x8*)((const char*)&lP[wave][0] + q * 128 +
                                   ((kc2 * 64 + l4 * 16) ^ ((q & 7) << 4)));
      __builtin_amdgcn_s_setprio(1);
#pragma unroll
      for (int nd = 0; nd < 16; nd++) {
        int d = nd * 16 + l15;
        bf16x8 vf = *(const bf16x8*)((const char*)&lV[d * 64] +
                                     ((kc2 * 64 + l4 * 16) ^ ((d & 7) << 4)));
        acc[nd] = __builtin_amdgcn_mfma_f32_16x16x32_bf16(pa, vf, acc[nd], 0, 0, 0);
      }
      __builtin_amdgcn_s_setprio(0);
    }
    __syncthreads();
  }
  float rinv[4];
#pragma unroll
  for (int r = 0; r < 4; r++) rinv[r] = 1.0f / lrow[r];
#pragma unroll
  for (int nd = 0; nd < 16; nd++)
#pragma unroll
    for (int r = 0; r < 4; r++) {
      size_t row = qw + l4 * 4 + r;
      aout[row * AO_N + head * HD + nd * 16 + l15] = f2bf(acc[nd][r] * rinv[r]);
    }
#undef STAGE_KV
}

extern "C" void kernel_launch(void* const* d_in, const int* in_sizes, int n_in,
                              void* d_out, int out_size, void* d_ws, size_t ws_size,
                              hipStream_t stream) {
  const float* x = (const float*)d_in[0];
  const int* pos = (const int*)d_in[1];
  const float* wq = (const float*)d_in[2];
  const float* wk = (const float*)d_in[3];
  const float* wv = (const float*)d_in[4];
  const float* wo = (const float*)d_in[5];
  const float* qnw = (const float*)d_in[6];
  const float* knw = (const float*)d_in[7];

  // scratch layout:
  //   d_out: qkv bf16 [4096][4096] (overwritten by final fp32 GEMM)
  //   ws+0        : x bf16 [4096][2304]; later aout bf16 [4096][2048]
  //   ws+18874368 : W^T bf16 (qkv-phase: [4096][2304]; out-phase: wo^T [2304][2048])
  //   ws+28311552 : vt bf16 [4][256][4096]
  u16* qkv = (u16*)d_out;
  u16* xbf = (u16*)d_ws;
  u16* wT = (u16*)((char*)d_ws + 18874368);
  u16* vtb = (u16*)((char*)d_ws + 28311552);
  u16* aout = xbf;

  k_cvt_bf16<<<9216, 256, 0, stream>>>(x, xbf, S_LEN * HID_DIM);
  k_transpose_cvt<<<dim3(64, 72), 256, 0, stream>>>(wq, 2048, wT, HID_DIM, 0);
  k_transpose_cvt<<<dim3(32, 72), 256, 0, stream>>>(wk, 1024, wT, HID_DIM, 2048);
  k_transpose_cvt<<<dim3(32, 72), 256, 0, stream>>>(wv, 1024, wT, HID_DIM, 3072);
  k_gemm256<1><<<dim3(256), 512, 0, stream>>>(xbf, wT, qkv, S_LEN, QKV_N, HID_DIM);
  k_vtrans<<<dim3(32, 128), 256, 0, stream>>>(qkv, vtb);
  k_normrope<<<S_LEN * 12, 128, 0, stream>>>(qkv, pos, qnw, knw);
  k_attn<<<dim3(512), 256, 0, stream>>>(qkv, vtb, pos, aout);
  k_transpose_cvt<<<dim3(72, 64), 256, 0, stream>>>(wo, HID_DIM, wT, 2048, 0);
  k_gemm256<0><<<dim3(144), 512, 0, stream>>>(aout, wT, d_out, S_LEN, HID_DIM, 2048);
}